// Round 8
// baseline (247.781 us; speedup 1.0000x reference)
//
#include <hip/hip_runtime.h>

#define N_NODES 16384
#define N_EDGES 262144
#define BATCH   256
#define F_OUT   32
#define K_ORD   4
#define NCHUNK  8      // batch chunks == XCD count
#define CHUNK   32     // batch lanes per chunk
#define NPB     8      // nodes per iteration (8 nodes x 32 lanes = 256 thr)
#define GRID_P  2048   // persistent blocks: 8/CU x 256 CU
#define NGRP    (N_NODES / NPB)          // 2048 node groups
#define GPB     (NGRP / (GRID_P / NCHUNK))  // 8 groups per block

typedef float f32x4 __attribute__((ext_vector_type(4)));

// ---------------- transpose: x (B,N) -> xT (N,B) ----------------
__global__ void transpose_kernel(const float* __restrict__ x, float* __restrict__ xT) {
    __shared__ float tile[32][33];
    int tx = threadIdx.x;          // 0..31
    int ty = threadIdx.y;          // 0..7
    int n0 = blockIdx.x * 32;
    int b0 = blockIdx.y * 32;
#pragma unroll
    for (int j = 0; j < 4; ++j) {
        int b = b0 + ty + j * 8;
        int n = n0 + tx;
        tile[ty + j * 8][tx] = x[(size_t)b * N_NODES + n];
    }
    __syncthreads();
#pragma unroll
    for (int j = 0; j < 4; ++j) {
        int n = n0 + ty + j * 8;
        int b = b0 + tx;
        xT[(size_t)n * BATCH + b] = tile[tx][ty + j * 8];
    }
}

// ---------------- CSR build ----------------
__global__ void hist_kernel(const int* __restrict__ rows, int* __restrict__ count) {
    int e = blockIdx.x * blockDim.x + threadIdx.x;
    if (e < N_EDGES) atomicAdd(&count[rows[e]], 1);
}

__global__ void scan_kernel(int* __restrict__ count, int* __restrict__ row_ptr) {
    __shared__ int part[256];
    int t = threadIdx.x;
    int base = t * 64;
    int loc[64];
    int s = 0;
#pragma unroll
    for (int i = 0; i < 64; ++i) { loc[i] = count[base + i]; s += loc[i]; }
    part[t] = s;
    __syncthreads();
    for (int d = 1; d < 256; d <<= 1) {
        int v = (t >= d) ? part[t - d] : 0;
        __syncthreads();
        part[t] += v;
        __syncthreads();
    }
    int off = part[t] - s;  // exclusive prefix
#pragma unroll
    for (int i = 0; i < 64; ++i) {
        row_ptr[base + i] = off;
        count[base + i] = off;   // becomes the scatter cursor
        off += loc[i];
    }
    if (t == 255) row_ptr[N_NODES] = off;   // == N_EDGES
}

__global__ void scatter_kernel(const int* __restrict__ rows, const int* __restrict__ cols,
                               const float* __restrict__ vals,
                               int* __restrict__ cursor,
                               int* __restrict__ csr_col, float* __restrict__ csr_val) {
    int e = blockIdx.x * blockDim.x + threadIdx.x;
    if (e < N_EDGES) {
        int r = rows[e];
        int pos = atomicAdd(&cursor[r], 1);
        csr_col[pos] = cols[e];
        csr_val[pos] = vals[e];
    }
}

// ---------------- Chebyshev step, persistent XCD-chunked ----------------
// 2048 blocks = initial dispatch fill (round-robin -> chunk==XCD, stable for kernel
// lifetime). Block handles chunk = bid&7, grid-strides over GPB node-groups.
__global__ void __launch_bounds__(256, 8)
cheb_kernel(const float* __restrict__ in, const float* __restrict__ prev,
            float* __restrict__ out,
            const int* __restrict__ row_ptr,
            const float* __restrict__ csr_val, const int* __restrict__ csr_col,
            float c) {
    int chunk = blockIdx.x & (NCHUNK - 1);
    int bslot = blockIdx.x >> 3;               // 0..255
    int nsub  = threadIdx.x >> 5;
    int b     = chunk * CHUNK + (threadIdx.x & 31);
    for (int g = 0; g < GPB; ++g) {
        int n = (bslot + g * 256) * NPB + nsub;
        int beg = row_ptr[n], end = row_ptr[n + 1];
        float acc = 0.f;
        int e = beg;
        for (; e + 3 < end; e += 4) {
            int   c0 = csr_col[e],     c1 = csr_col[e + 1], c2 = csr_col[e + 2], c3 = csr_col[e + 3];
            float v0 = csr_val[e],     v1 = csr_val[e + 1], v2 = csr_val[e + 2], v3 = csr_val[e + 3];
            acc += v0 * in[(size_t)c0 * BATCH + b];
            acc += v1 * in[(size_t)c1 * BATCH + b];
            acc += v2 * in[(size_t)c2 * BATCH + b];
            acc += v3 * in[(size_t)c3 * BATCH + b];
        }
        for (; e < end; ++e)
            acc += csr_val[e] * in[(size_t)csr_col[e] * BATCH + b];
        size_t idx = (size_t)n * BATCH + b;
        float o = c * (acc - in[idx]);
        if (prev) o -= prev[idx];
        out[idx] = o;
    }
}

// ---------------- fused final, persistent XCD-chunked ----------------
__global__ void __launch_bounds__(256, 8)
final_kernel(const float* __restrict__ t0, const float* __restrict__ t1,
             const float* __restrict__ t2,
             const int* __restrict__ row_ptr,
             const float* __restrict__ csr_val, const int* __restrict__ csr_col,
             const float* __restrict__ weight, const float* __restrict__ bias,
             float* __restrict__ out) {
    __shared__ float w[F_OUT * K_ORD];
    __shared__ float bb[F_OUT];
    __shared__ f32x4 tval[NPB][CHUNK];
    int tid = threadIdx.x;
    if (tid < F_OUT * K_ORD) w[tid] = weight[tid];
    if (tid < F_OUT) bb[tid] = bias[tid];
    __syncthreads();

    int chunk = blockIdx.x & (NCHUNK - 1);
    int bslot = blockIdx.x >> 3;

    // phase-1 thread mapping
    int p1_nsub = tid >> 5;
    int p1_bi   = tid & 31;
    int p1_b    = chunk * CHUNK + p1_bi;
    // phase-2 thread mapping (f const per thread -> weights in registers)
    int f = (tid & 7) * 4;
    f32x4 w0 = *(const f32x4*)&w[(f + 0) * 4];
    f32x4 w1 = *(const f32x4*)&w[(f + 1) * 4];
    f32x4 w2 = *(const f32x4*)&w[(f + 2) * 4];
    f32x4 w3 = *(const f32x4*)&w[(f + 3) * 4];
    f32x4 b4 = *(const f32x4*)&bb[f];
    int p2_nsub = (tid >> 3) & 7;
    int p2_wv   = tid >> 6;

    for (int g = 0; g < GPB; ++g) {
        int ng = bslot + g * 256;
        {
            int n = ng * NPB + p1_nsub;
            int beg = row_ptr[n], end = row_ptr[n + 1];
            float acc = 0.f;
            int e = beg;
            for (; e + 3 < end; e += 4) {
                int   c0 = csr_col[e],     c1 = csr_col[e + 1], c2 = csr_col[e + 2], c3 = csr_col[e + 3];
                float v0 = csr_val[e],     v1 = csr_val[e + 1], v2 = csr_val[e + 2], v3 = csr_val[e + 3];
                acc += v0 * t2[(size_t)c0 * BATCH + p1_b];
                acc += v1 * t2[(size_t)c1 * BATCH + p1_b];
                acc += v2 * t2[(size_t)c2 * BATCH + p1_b];
                acc += v3 * t2[(size_t)c3 * BATCH + p1_b];
            }
            for (; e < end; ++e)
                acc += csr_val[e] * t2[(size_t)csr_col[e] * BATCH + p1_b];

            size_t idx = (size_t)n * BATCH + p1_b;
            float t2v = t2[idx];
            float t3v = 2.f * (acc - t2v) - t1[idx];
            tval[p1_nsub][p1_bi] = (f32x4){t0[idx], t1[idx], t2v, t3v};
        }
        __syncthreads();

        size_t n = (size_t)(ng * NPB + p2_nsub);
#pragma unroll
        for (int i = 0; i < 8; ++i) {
            int b_idx = i * 4 + p2_wv;                   // 0..31
            size_t b  = (size_t)(chunk * CHUNK + b_idx);
            f32x4 tv = tval[p2_nsub][b_idx];
            f32x4 r;
            r.x = w0.x * tv.x + w0.y * tv.y + w0.z * tv.z + w0.w * tv.w + b4.x;
            r.y = w1.x * tv.x + w1.y * tv.y + w1.z * tv.z + w1.w * tv.w + b4.y;
            r.z = w2.x * tv.x + w2.y * tv.y + w2.z * tv.z + w2.w * tv.w + b4.z;
            r.w = w3.x * tv.x + w3.y * tv.y + w3.z * tv.z + w3.w * tv.w + b4.w;
            __builtin_nontemporal_store(r, (f32x4*)(out + (b * N_NODES + n) * F_OUT + f));
        }
        __syncthreads();   // protect tval before next iteration overwrites
    }
}

extern "C" void kernel_launch(void* const* d_in, const int* in_sizes, int n_in,
                              void* d_out, int out_size, void* d_ws, size_t ws_size,
                              hipStream_t stream) {
    const float* x      = (const float*)d_in[0];
    const float* vals   = (const float*)d_in[1];
    const int*   rows   = (const int*)d_in[2];
    const int*   cols   = (const int*)d_in[3];
    const float* weight = (const float*)d_in[4];
    const float* bias   = (const float*)d_in[5];
    float* out = (float*)d_out;

    const size_t NB = (size_t)N_NODES * BATCH;   // 4,194,304 floats
    float* xT      = (float*)d_ws;
    float* t1      = xT + NB;
    float* t2      = t1 + NB;
    int*   row_ptr = (int*)(t2 + NB);            // N_NODES+1 (pad to 16448)
    int*   cursor  = row_ptr + 16448;            // N_NODES ints; also the histogram
    float* csr_val = (float*)(cursor + N_NODES);
    int*   csr_col = (int*)(csr_val + N_EDGES);

    (void)hipMemsetAsync(cursor, 0, N_NODES * sizeof(int), stream);

    transpose_kernel<<<dim3(N_NODES / 32, BATCH / 32), dim3(32, 8), 0, stream>>>(x, xT);
    hist_kernel<<<N_EDGES / 256, 256, 0, stream>>>(rows, cursor);
    scan_kernel<<<1, 256, 0, stream>>>(cursor, row_ptr);
    scatter_kernel<<<N_EDGES / 256, 256, 0, stream>>>(rows, cols, vals, cursor, csr_col, csr_val);

    cheb_kernel<<<GRID_P, 256, 0, stream>>>(xT, nullptr, t1, row_ptr, csr_val, csr_col, 1.f);
    cheb_kernel<<<GRID_P, 256, 0, stream>>>(t1, xT, t2, row_ptr, csr_val, csr_col, 2.f);
    final_kernel<<<GRID_P, 256, 0, stream>>>(xT, t1, t2, row_ptr, csr_val, csr_col,
                                             weight, bias, out);
}